// Round 5
// baseline (347.174 us; speedup 1.0000x reference)
//
#include <hip/hip_runtime.h>

// Atom_Atom_embedding_MP: batched KNN (k=16, self-excluded) + 3 message-passing
// layers (concat-features -> 33x33 matvec -> leakyrelu -> sum_k -> 33x16 matvec
// -> GroupNorm(2) -> leakyrelu -> residual).
//
// R1 (resubmitted R2-R4 after infra failures): knn rewritten from per-lane
// sorted top-16 (16-deep shift insert fired nearly every wave-iteration via
// divergence coupling -> ~108 instrs/64 pairs) to a wave-uniform threshold
// filter + LDS candidate queue + rare extract-min merges (~4-6/query).
// LDS 32KB -> 4KB (occupancy 41% -> ~full).

#define N_PTS 16384
#define D 16
#define DIN 33
#define NEG 0.2f
#define GEPS 1e-5f
#define INFF 3.0e38f

__global__ __launch_bounds__(256) void prep_kernel(const float* __restrict__ x,
                                                   float4* __restrict__ xyz4, int n) {
  int i = blockIdx.x * 256 + threadIdx.x;
  if (i < n) xyz4[i] = make_float4(x[3*i], x[3*i+1], x[3*i+2], 0.f);
}

// Extract the 16 smallest of (queue[0:count] ∪ top16) across the wave.
// t_d2/t_idx live on lanes 0-15. Updates tau = new 16th smallest.
__device__ __forceinline__ void knn_merge(float* __restrict__ qd, int* __restrict__ qi,
                                          int count, float& t_d2, int& t_idx,
                                          float& tau, int l) {
  __asm__ volatile("s_waitcnt lgkmcnt(0)" ::: "memory");  // queue writes visible
  float e0 = INFF; int i0 = -1 - l;      // unique pad keys (never real, break ties)
  float e1 = INFF; int i1 = -65 - l;
  if (l < count)      { e0 = qd[l];      i0 = qi[l]; }
  if (l + 64 < count) { e1 = qd[l + 64]; i1 = qi[l + 64]; }
  float e2 = (l < 16) ? t_d2  : INFF;
  int   i2 = (l < 16) ? t_idx : (-129 - l);
  float nd = INFF; int ni = -1;
  for (int r = 0; r < 16; ++r) {
    // local min of (e0,e1,e2), slot-tracked
    float bv = e0; int bi = i0; int bs = 0;
    if (e1 < bv || (e1 == bv && i1 < bi)) { bv = e1; bi = i1; bs = 1; }
    if (e2 < bv || (e2 == bv && i2 < bi)) { bv = e2; bi = i2; bs = 2; }
    const float lv = bv; const int li = bi; const int ls = bs;
#pragma unroll
    for (int m = 1; m < 64; m <<= 1) {
      float ov = __shfl_xor(bv, m);
      int   oi = __shfl_xor(bi, m);
      if (ov < bv || (ov == bv && oi < bi)) { bv = ov; bi = oi; }
    }
    // unique winner ((v,idx) pairs are distinct) nulls its slot
    if (lv == bv && li == bi) {
      if (ls == 0)      { e0 = INFF; i0 = -1 - l; }
      else if (ls == 1) { e1 = INFF; i1 = -65 - l; }
      else              { e2 = INFF; i2 = -129 - l; }
    }
    if (l == r) { nd = bv; ni = bi; }
  }
  t_d2 = nd; t_idx = ni;          // lanes 0-15 hold the new top-16 (ascending)
  tau = __shfl(nd, 15);           // 16th smallest so far
}

__global__ __launch_bounds__(256) void knn_kernel(const float4* __restrict__ xyz4,
                                                  const int* __restrict__ batch,
                                                  int* __restrict__ knn_idx,
                                                  float* __restrict__ knn_d2, int n) {
  __shared__ float qd[4][128];
  __shared__ int   qi[4][128];
  const int tid = threadIdx.x;
  const int w = tid >> 6;
  const int l = tid & 63;
  const int q = blockIdx.x * 4 + w;

  const float4 Q = xyz4[q];
  const int b = batch[q];
  int lo, hi;
  { int a = 0, c = n; while (a < c) { int m = (a + c) >> 1; if (batch[m] <  b) a = m + 1; else c = m; } lo = a; }
  { int a = lo, c = n; while (a < c) { int m = (a + c) >> 1; if (batch[m] <= b) a = m + 1; else c = m; } hi = a; }

  const unsigned long long lmask = (1ull << l) - 1ull;
  float tau = INFF;
  int count = 0;                    // wave-uniform (ballot-derived)
  float t_d2 = INFF; int t_idx = q;

  for (int j0 = lo; j0 < hi; j0 += 64) {
    const int j = j0 + l;
    bool pass = false; float d2 = 0.f;
    if (j < hi) {
      float4 P = xyz4[j];
      float dx = Q.x - P.x, dy = Q.y - P.y, dz = Q.z - P.z;
      d2 = dx*dx + dy*dy + dz*dz;
      pass = (d2 < tau) && (j != q);
    }
    unsigned long long m = __ballot(pass);
    if (m) {
      if (pass) {
        int pos = count + __popcll(m & lmask);
        qd[w][pos] = d2; qi[w][pos] = j;
      }
      count += __popcll(m);
      if (count >= 64) {            // capacity 128: pre-append count<=63, +64 max
        knn_merge(&qd[w][0], &qi[w][0], count, t_d2, t_idx, tau, l);
        count = 0;
      }
    }
  }
  if (count > 0) knn_merge(&qd[w][0], &qi[w][0], count, t_d2, t_idx, tau, l);

  if (l < 16) {
    knn_idx[q * 16 + l] = t_idx;
    knn_d2 [q * 16 + l] = t_d2;
  }
}

__device__ __forceinline__ void load16(const float4* __restrict__ base, int row, float* dst) {
  float4 a = base[row*4+0], b = base[row*4+1], c = base[row*4+2], d = base[row*4+3];
  dst[0]=a.x;  dst[1]=a.y;  dst[2]=a.z;  dst[3]=a.w;
  dst[4]=b.x;  dst[5]=b.y;  dst[6]=b.z;  dst[7]=b.w;
  dst[8]=c.x;  dst[9]=c.y;  dst[10]=c.z; dst[11]=c.w;
  dst[12]=d.x; dst[13]=d.y; dst[14]=d.z; dst[15]=d.w;
}

__device__ __forceinline__ float lrelu(float x) {
  return fmaxf(x, 0.f) + NEG * fminf(x, 0.f);
}

__global__ __launch_bounds__(256) void layer_kernel(
    const float* __restrict__ in, const int* __restrict__ knn_idx,
    const float* __restrict__ knn_d2,
    const float* __restrict__ W1, const float* __restrict__ b1,
    const float* __restrict__ W2, const float* __restrict__ b2,
    const float* __restrict__ gamma, const float* __restrict__ beta,
    float* __restrict__ outb) {
  __shared__ float sW2[DIN * D];
  __shared__ float sb2[D], sg[D], sbt[D];
  const int tid = threadIdx.x;
  for (int t = tid; t < DIN * D; t += 256) sW2[t] = W2[t];
  if (tid < D) { sb2[tid] = b2[tid]; sg[tid] = gamma[tid]; sbt[tid] = beta[tid]; }
  __syncthreads();

  const int p = blockIdx.x * 16 + (tid >> 4);  // point
  const int c = tid & 15;                       // lane-col == neighbor index k
  const float4* in4 = (const float4*)in;

  float s[16], nf[16];
  load16(in4, p, s);
  const int   nb = knn_idx[p * 16 + c];
  const float dk = knn_d2 [p * 16 + c];
  load16(in4, nb, nf);

  float h[DIN];
#pragma unroll
  for (int o = 0; o < DIN; ++o) h[o] = b1[o] + dk * W1[32 * DIN + o];
#pragma unroll
  for (int i = 0; i < 16; ++i) {
    const float si = s[i], ni = nf[i];
#pragma unroll
    for (int o = 0; o < DIN; ++o) {
      h[o] += si * W1[i * DIN + o];
      h[o] += ni * W1[(16 + i) * DIN + o];
    }
  }
#pragma unroll
  for (int o = 0; o < DIN; ++o) h[o] = lrelu(h[o]);

#pragma unroll
  for (int o = 0; o < DIN; ++o) {
    float x = h[o];
    x += __shfl_xor(x, 1);
    x += __shfl_xor(x, 2);
    x += __shfl_xor(x, 4);
    x += __shfl_xor(x, 8);
    h[o] = x;
  }

  float m = sb2[c];
#pragma unroll
  for (int i = 0; i < DIN; ++i) m += h[i] * sW2[i * D + c];

  float sum = m;
  sum += __shfl_xor(sum, 1); sum += __shfl_xor(sum, 2); sum += __shfl_xor(sum, 4);
  const float mu = sum * 0.125f;
  const float dd = m - mu;
  float sq = dd * dd;
  sq += __shfl_xor(sq, 1); sq += __shfl_xor(sq, 2); sq += __shfl_xor(sq, 4);
  const float var = sq * 0.125f;
  float yv = dd * (1.0f / sqrtf(var + GEPS));
  yv = yv * sg[c] + sbt[c];

  const float selfc = in[p * 16 + c];
  outb[p * 16 + c] = selfc + lrelu(yv);
}

extern "C" void kernel_launch(void* const* d_in, const int* in_sizes, int n_in,
                              void* d_out, int out_size, void* d_ws, size_t ws_size,
                              hipStream_t stream) {
  const float* x     = (const float*)d_in[0];
  const float* yat   = (const float*)d_in[2];
  const float* W1    = (const float*)d_in[3];
  const float* b1    = (const float*)d_in[4];
  const float* W2    = (const float*)d_in[5];
  const float* b2    = (const float*)d_in[6];
  const float* gamma = (const float*)d_in[7];
  const float* beta  = (const float*)d_in[8];
  const int*   xb    = (const int*)d_in[9];
  float* out = (float*)d_out;

  char* ws = (char*)d_ws;
  float4* xyz4 = (float4*)(ws);
  int*    kidx = (int*)  (ws + 262144);
  float*  kd2  = (float*)(ws + 262144 + 1048576);
  float*  bufA = (float*)(ws + 262144 + 2*1048576);
  float*  bufB = (float*)(ws + 262144 + 3*1048576);

  prep_kernel<<<N_PTS / 256, 256, 0, stream>>>(x, xyz4, N_PTS);
  knn_kernel<<<N_PTS / 4, 256, 0, stream>>>(xyz4, xb, kidx, kd2, N_PTS);
  layer_kernel<<<N_PTS / 16, 256, 0, stream>>>(yat,  kidx, kd2,
      W1 + 0*DIN*DIN, b1 + 0*DIN, W2 + 0*DIN*D, b2 + 0*D, gamma + 0*D, beta + 0*D, bufA);
  layer_kernel<<<N_PTS / 16, 256, 0, stream>>>(bufA, kidx, kd2,
      W1 + 1*DIN*DIN, b1 + 1*DIN, W2 + 1*DIN*D, b2 + 1*D, gamma + 1*D, beta + 1*D, bufB);
  layer_kernel<<<N_PTS / 16, 256, 0, stream>>>(bufB, kidx, kd2,
      W1 + 2*DIN*DIN, b1 + 2*DIN, W2 + 2*DIN*D, b2 + 2*D, gamma + 2*D, beta + 2*D, out);
}

// Round 7
// 234.312 us; speedup vs baseline: 1.4817x; 1.4817x over previous
//
#include <hip/hip_runtime.h>

// Atom_Atom_embedding_MP: batched KNN (k=16, self-excluded) + 3 message-passing
// layers (concat -> 33x33 matvec -> leakyrelu -> sum_k -> 33x16 matvec
// -> GroupNorm(2) -> leakyrelu -> residual).
//
// R5 (resubmitted R6 after infra failure): R1 post-mortem showed duration flat
// (233->243us) because selection machinery (knn_merge ~2.2K cyc x ~5/query from
// tau staleness) dominated, not the scan. New scheme: LDS candidate pool (cap
// 256) + tau tightened by 12-step VALUE-DOMAIN BISECTION (4 ballots/step,
// ~300cyc) + ballot-compact; exact 16-extract runs ONCE at the end. Invariant:
// count(d2<tau)>=16 so no true top-16 member is ever dropped.

#define N_PTS 16384
#define D 16
#define DIN 33
#define NEG 0.2f
#define GEPS 1e-5f
#define INFF 3.0e38f
#define SHRINK_AT 192

__global__ __launch_bounds__(256) void prep_kernel(const float* __restrict__ x,
                                                   float4* __restrict__ xyz4, int n) {
  int i = blockIdx.x * 256 + threadIdx.x;
  if (i < n) xyz4[i] = make_float4(x[3*i], x[3*i+1], x[3*i+2], 0.f);
}

// Tighten tau (keep count(d2<tau)>=16) by value-domain bisection, then
// compact pool to entries < tau. Returns new pool count (>=16).
__device__ __forceinline__ int pool_shrink(float* __restrict__ pd, int* __restrict__ pi,
                                           int pcount, float& tau, int l,
                                           unsigned long long lmask) {
  __asm__ volatile("s_waitcnt lgkmcnt(0)" ::: "memory");  // appends visible
  float e0 = INFF, e1 = INFF, e2 = INFF, e3 = INFF;
  int   j0 = 0, j1 = 0, j2 = 0, j3 = 0;
  const bool p0 = l < pcount, p1 = l + 64 < pcount, p2 = l + 128 < pcount, p3 = l + 192 < pcount;
  if (p0) { e0 = pd[l];       j0 = pi[l]; }
  if (p1) { e1 = pd[l + 64];  j1 = pi[l + 64]; }
  if (p2) { e2 = pd[l + 128]; j2 = pi[l + 128]; }
  if (p3) { e3 = pd[l + 192]; j3 = pi[l + 192]; }
  // hi = wave-max of present entries (pads -> 0, d2 >= 0)
  float mx = fmaxf(fmaxf(p0 ? e0 : 0.f, p1 ? e1 : 0.f), fmaxf(p2 ? e2 : 0.f, p3 ? e3 : 0.f));
#pragma unroll
  for (int m = 1; m < 64; m <<= 1) mx = fmaxf(mx, __shfl_xor(mx, m));
  float lo = 0.f, hi = mx * 1.000001f + 1e-35f;   // count(<hi) == pcount >= 16
  for (int it = 0; it < 12; ++it) {
    const float mid = 0.5f * (lo + hi);
    const int c = __popcll(__ballot(e0 < mid)) + __popcll(__ballot(e1 < mid))
                + __popcll(__ballot(e2 < mid)) + __popcll(__ballot(e3 < mid));
    if (c >= 16) hi = mid; else lo = mid;          // keep count(<hi)>=16
  }
  tau = hi;
  int base = 0;
  { const bool k = e0 < tau; const unsigned long long m = __ballot(k);
    if (k) { const int pos = base + __popcll(m & lmask); pd[pos] = e0; pi[pos] = j0; }
    base += __popcll(m); }
  { const bool k = e1 < tau; const unsigned long long m = __ballot(k);
    if (k) { const int pos = base + __popcll(m & lmask); pd[pos] = e1; pi[pos] = j1; }
    base += __popcll(m); }
  { const bool k = e2 < tau; const unsigned long long m = __ballot(k);
    if (k) { const int pos = base + __popcll(m & lmask); pd[pos] = e2; pi[pos] = j2; }
    base += __popcll(m); }
  { const bool k = e3 < tau; const unsigned long long m = __ballot(k);
    if (k) { const int pos = base + __popcll(m & lmask); pd[pos] = e3; pi[pos] = j3; }
    base += __popcll(m); }
  return base;
}

// Exact ascending top-16 of the pool via 16-round extract-min (once per query).
__device__ __forceinline__ void pool_extract16(const float* __restrict__ pd,
                                               const int* __restrict__ pi,
                                               int pcount, int q, int l,
                                               int* __restrict__ knn_idx,
                                               float* __restrict__ knn_d2) {
  __asm__ volatile("s_waitcnt lgkmcnt(0)" ::: "memory");
  float e0 = INFF, e1 = INFF, e2 = INFF, e3 = INFF;
  int   j0 = -1 - l, j1 = -65 - l, j2 = -129 - l, j3 = -193 - l;  // unique pads
  if (l       < pcount) { e0 = pd[l];       j0 = pi[l]; }
  if (l + 64  < pcount) { e1 = pd[l + 64];  j1 = pi[l + 64]; }
  if (l + 128 < pcount) { e2 = pd[l + 128]; j2 = pi[l + 128]; }
  if (l + 192 < pcount) { e3 = pd[l + 192]; j3 = pi[l + 192]; }
  float rv = 0.f; int ri = q;
  for (int r = 0; r < 16; ++r) {
    float bv = e0; int bi = j0; int bs = 0;
    if (e1 < bv || (e1 == bv && j1 < bi)) { bv = e1; bi = j1; bs = 1; }
    if (e2 < bv || (e2 == bv && j2 < bi)) { bv = e2; bi = j2; bs = 2; }
    if (e3 < bv || (e3 == bv && j3 < bi)) { bv = e3; bi = j3; bs = 3; }
    const float lv = bv; const int li = bi;
#pragma unroll
    for (int m = 1; m < 64; m <<= 1) {
      const float ov = __shfl_xor(bv, m);
      const int   oi = __shfl_xor(bi, m);
      if (ov < bv || (ov == bv && oi < bi)) { bv = ov; bi = oi; }
    }
    if (lv == bv && li == bi) {       // unique winner nulls its slot
      if (bs == 0)      { e0 = INFF; j0 = -1 - l; }
      else if (bs == 1) { e1 = INFF; j1 = -65 - l; }
      else if (bs == 2) { e2 = INFF; j2 = -129 - l; }
      else              { e3 = INFF; j3 = -193 - l; }
    }
    if (l == r) { rv = bv; ri = bi; }
  }
  if (l < 16) {
    knn_idx[q * 16 + l] = ri;
    knn_d2 [q * 16 + l] = rv;
  }
}

__global__ __launch_bounds__(256) void knn_kernel(const float4* __restrict__ xyz4,
                                                  const int* __restrict__ batch,
                                                  int* __restrict__ knn_idx,
                                                  float* __restrict__ knn_d2, int n) {
  __shared__ float pd[4][256];
  __shared__ int   pi[4][256];
  const int tid = threadIdx.x;
  const int w = tid >> 6;
  const int l = tid & 63;
  const int q = blockIdx.x * 4 + w;

  const float4 Q = xyz4[q];
  const int b = batch[q];
  int lo, hi;
  { int a = 0, c = n; while (a < c) { int m = (a + c) >> 1; if (batch[m] <  b) a = m + 1; else c = m; } lo = a; }
  { int a = lo, c = n; while (a < c) { int m = (a + c) >> 1; if (batch[m] <= b) a = m + 1; else c = m; } hi = a; }

  const unsigned long long lmask = (1ull << l) - 1ull;
  float tau = INFF;
  int pcount = 0;                     // wave-uniform (ballot-derived)

  for (int j0 = lo; j0 < hi; j0 += 64) {
    const int j = j0 + l;
    bool pass = false; float d2 = 0.f;
    if (j < hi) {
      const float4 P = xyz4[j];
      const float dx = Q.x - P.x, dy = Q.y - P.y, dz = Q.z - P.z;
      d2 = dx*dx + dy*dy + dz*dz;
      pass = (d2 < tau) && (j != q);
    }
    const unsigned long long m = __ballot(pass);
    if (m) {
      if (pass) {
        const int pos = pcount + __popcll(m & lmask);
        pd[w][pos] = d2; pi[w][pos] = j;
      }
      pcount += __popcll(m);
      if (pcount >= SHRINK_AT) {      // cap 256: pre-append <=191, +64 max
        pcount = pool_shrink(&pd[w][0], &pi[w][0], pcount, tau, l, lmask);
      }
    }
  }
  pool_extract16(&pd[w][0], &pi[w][0], pcount, q, l, knn_idx, knn_d2);
}

__device__ __forceinline__ void load16(const float4* __restrict__ base, int row, float* dst) {
  float4 a = base[row*4+0], b = base[row*4+1], c = base[row*4+2], d = base[row*4+3];
  dst[0]=a.x;  dst[1]=a.y;  dst[2]=a.z;  dst[3]=a.w;
  dst[4]=b.x;  dst[5]=b.y;  dst[6]=b.z;  dst[7]=b.w;
  dst[8]=c.x;  dst[9]=c.y;  dst[10]=c.z; dst[11]=c.w;
  dst[12]=d.x; dst[13]=d.y; dst[14]=d.z; dst[15]=d.w;
}

__device__ __forceinline__ float lrelu(float x) {
  return fmaxf(x, 0.f) + NEG * fminf(x, 0.f);
}

__global__ __launch_bounds__(256) void layer_kernel(
    const float* __restrict__ in, const int* __restrict__ knn_idx,
    const float* __restrict__ knn_d2,
    const float* __restrict__ W1, const float* __restrict__ b1,
    const float* __restrict__ W2, const float* __restrict__ b2,
    const float* __restrict__ gamma, const float* __restrict__ beta,
    float* __restrict__ outb) {
  __shared__ float sW2[DIN * D];
  __shared__ float sb2[D], sg[D], sbt[D];
  const int tid = threadIdx.x;
  for (int t = tid; t < DIN * D; t += 256) sW2[t] = W2[t];
  if (tid < D) { sb2[tid] = b2[tid]; sg[tid] = gamma[tid]; sbt[tid] = beta[tid]; }
  __syncthreads();

  const int p = blockIdx.x * 16 + (tid >> 4);  // point
  const int c = tid & 15;                       // lane-col == neighbor index k
  const float4* in4 = (const float4*)in;

  float s[16], nf[16];
  load16(in4, p, s);
  const int   nb = knn_idx[p * 16 + c];
  const float dk = knn_d2 [p * 16 + c];
  load16(in4, nb, nf);

  float h[DIN];
#pragma unroll
  for (int o = 0; o < DIN; ++o) h[o] = b1[o] + dk * W1[32 * DIN + o];
#pragma unroll
  for (int i = 0; i < 16; ++i) {
    const float si = s[i], ni = nf[i];
#pragma unroll
    for (int o = 0; o < DIN; ++o) {
      h[o] += si * W1[i * DIN + o];
      h[o] += ni * W1[(16 + i) * DIN + o];
    }
  }
#pragma unroll
  for (int o = 0; o < DIN; ++o) h[o] = lrelu(h[o]);

#pragma unroll
  for (int o = 0; o < DIN; ++o) {
    float x = h[o];
    x += __shfl_xor(x, 1);
    x += __shfl_xor(x, 2);
    x += __shfl_xor(x, 4);
    x += __shfl_xor(x, 8);
    h[o] = x;
  }

  float m = sb2[c];
#pragma unroll
  for (int i = 0; i < DIN; ++i) m += h[i] * sW2[i * D + c];

  float sum = m;
  sum += __shfl_xor(sum, 1); sum += __shfl_xor(sum, 2); sum += __shfl_xor(sum, 4);
  const float mu = sum * 0.125f;
  const float dd = m - mu;
  float sq = dd * dd;
  sq += __shfl_xor(sq, 1); sq += __shfl_xor(sq, 2); sq += __shfl_xor(sq, 4);
  const float var = sq * 0.125f;
  float yv = dd * (1.0f / sqrtf(var + GEPS));
  yv = yv * sg[c] + sbt[c];

  const float selfc = in[p * 16 + c];
  outb[p * 16 + c] = selfc + lrelu(yv);
}

extern "C" void kernel_launch(void* const* d_in, const int* in_sizes, int n_in,
                              void* d_out, int out_size, void* d_ws, size_t ws_size,
                              hipStream_t stream) {
  const float* x     = (const float*)d_in[0];
  const float* yat   = (const float*)d_in[2];
  const float* W1    = (const float*)d_in[3];
  const float* b1    = (const float*)d_in[4];
  const float* W2    = (const float*)d_in[5];
  const float* b2    = (const float*)d_in[6];
  const float* gamma = (const float*)d_in[7];
  const float* beta  = (const float*)d_in[8];
  const int*   xb    = (const int*)d_in[9];
  float* out = (float*)d_out;

  char* ws = (char*)d_ws;
  float4* xyz4 = (float4*)(ws);
  int*    kidx = (int*)  (ws + 262144);
  float*  kd2  = (float*)(ws + 262144 + 1048576);
  float*  bufA = (float*)(ws + 262144 + 2*1048576);
  float*  bufB = (float*)(ws + 262144 + 3*1048576);

  prep_kernel<<<N_PTS / 256, 256, 0, stream>>>(x, xyz4, N_PTS);
  knn_kernel<<<N_PTS / 4, 256, 0, stream>>>(xyz4, xb, kidx, kd2, N_PTS);
  layer_kernel<<<N_PTS / 16, 256, 0, stream>>>(yat,  kidx, kd2,
      W1 + 0*DIN*DIN, b1 + 0*DIN, W2 + 0*DIN*D, b2 + 0*D, gamma + 0*D, beta + 0*D, bufA);
  layer_kernel<<<N_PTS / 16, 256, 0, stream>>>(bufA, kidx, kd2,
      W1 + 1*DIN*DIN, b1 + 1*DIN, W2 + 1*DIN*D, b2 + 1*D, gamma + 1*D, beta + 1*D, bufB);
  layer_kernel<<<N_PTS / 16, 256, 0, stream>>>(bufB, kidx, kd2,
      W1 + 2*DIN*DIN, b1 + 2*DIN, W2 + 2*DIN*D, b2 + 2*D, gamma + 2*D, beta + 2*D, out);
}